// Round 5
// baseline (452.549 us; speedup 1.0000x reference)
//
#include <hip/hip_runtime.h>
#include <hip/hip_bf16.h>

#define NN 50000
#define EE 800000
#define SCAN_BLOCKS 196   // 196*256 = 50176 >= NN

typedef __bf16 bf16x8_t __attribute__((ext_vector_type(8)));
typedef float f32x4_t __attribute__((ext_vector_type(4)));

__device__ __forceinline__ float silu_f(float v) {
    return v * __builtin_amdgcn_rcpf(1.0f + __expf(-v));
}

// ---------------- prep: x -> bf16, weights -> transposed bf16 [n][k], dst histogram ----------------
__global__ void prep_kernel(const float* __restrict__ x,
                            const float* __restrict__ We1,
                            const float* __restrict__ We2,
                            const float* __restrict__ Wn1,
                            const float* __restrict__ Wn2,
                            const int* __restrict__ eidx,
                            __bf16* __restrict__ xb,
                            __bf16* __restrict__ We1T,
                            __bf16* __restrict__ We2T,
                            __bf16* __restrict__ Wn1T,
                            __bf16* __restrict__ Wn2T,
                            int* __restrict__ hist) {
    int tid = blockIdx.x * blockDim.x + threadIdx.x;
    int np = gridDim.x * blockDim.x;
    const int NX = NN * 128 / 4;
    for (int i = tid; i < NX; i += np) {
        float4 v = ((const float4*)x)[i];
        __bf16* o = xb + (size_t)i * 4;
        o[0] = (__bf16)v.x; o[1] = (__bf16)v.y; o[2] = (__bf16)v.z; o[3] = (__bf16)v.w;
    }
    for (int i = tid; i < 256 * 128; i += np) {
        int k = i >> 7, n = i & 127;
        We1T[n * 256 + k] = (__bf16)We1[i];
        Wn1T[n * 256 + k] = (__bf16)Wn1[i];
    }
    for (int i = tid; i < 128 * 128; i += np) {
        int k = i >> 7, n = i & 127;
        We2T[n * 128 + k] = (__bf16)We2[i];
        Wn2T[n * 128 + k] = (__bf16)Wn2[i];
    }
    for (int i = tid; i < EE; i += np) {
        atomicAdd(&hist[eidx[EE + i]], 1);
    }
}

// ---------------- counting-sort scan (3 tiny kernels) ----------------
__global__ void scan_a(const int* __restrict__ hist, int* __restrict__ bsum) {
    __shared__ int sh[256];
    int i = blockIdx.x * 256 + threadIdx.x;
    sh[threadIdx.x] = (i < NN) ? hist[i] : 0;
    __syncthreads();
    for (int s = 128; s > 0; s >>= 1) {
        if (threadIdx.x < s) sh[threadIdx.x] += sh[threadIdx.x + s];
        __syncthreads();
    }
    if (threadIdx.x == 0) bsum[blockIdx.x] = sh[0];
}

__global__ void scan_b(int* __restrict__ bsum) {
    __shared__ int sh[SCAN_BLOCKS];
    int t = threadIdx.x;
    if (t < SCAN_BLOCKS) sh[t] = bsum[t];
    __syncthreads();
    if (t == 0) {
        int acc = 0;
        for (int i = 0; i < SCAN_BLOCKS; ++i) { int v = sh[i]; sh[i] = acc; acc += v; }
    }
    __syncthreads();
    if (t < SCAN_BLOCKS) bsum[t] = sh[t];
}

__global__ void scan_c(const int* __restrict__ hist, const int* __restrict__ bsum,
                       int* __restrict__ off, int* __restrict__ cursor) {
    __shared__ int sh[256];
    int tx = threadIdx.x;
    int i = blockIdx.x * 256 + tx;
    int v = (i < NN) ? hist[i] : 0;
    sh[tx] = v;
    __syncthreads();
    for (int s = 1; s < 256; s <<= 1) {
        int add = (tx >= s) ? sh[tx - s] : 0;
        __syncthreads();
        sh[tx] += add;
        __syncthreads();
    }
    int excl = sh[tx] - v + bsum[blockIdx.x];
    if (i < NN) { off[i] = excl; cursor[i] = excl; }
    if (i == NN - 1) off[NN] = excl + v;
}

// ---------------- scatter: build sorted per-edge records ----------------
__global__ void scatter_kernel(const int* __restrict__ eidx,
                               const float* __restrict__ pos,
                               const float* __restrict__ eattr,
                               const float* __restrict__ s,
                               int* __restrict__ cursor,
                               float4* __restrict__ e_geo,
                               int2* __restrict__ e_nodes,
                               float2* __restrict__ e_gate) {
    int i = blockIdx.x * blockDim.x + threadIdx.x;
    if (i < EE) {
        int si = eidx[i];
        int di = eidx[EE + i];
        int p = atomicAdd(&cursor[di], 1);
        float dx = pos[di * 3 + 0] - pos[si * 3 + 0];
        float dy = pos[di * 3 + 1] - pos[si * 3 + 1];
        float dz = pos[di * 3 + 2] - pos[si * 3 + 2];
        e_geo[p] = make_float4(dx, dy, dz, dx * dx + dy * dy + dz * dz);
        e_nodes[p] = make_int2(si, di);
        e_gate[p] = make_float2(eattr[i], s[si]);
    }
}

// ---------------- edge kernel v5: wave-owns-outcols, reg weights, LDS x dbuf ----------------
// block = 256 threads (4 waves), tile = 128 sorted edges.
// Wave w computes outcols [32w, 32w+32) for all 128 edges.
// A-operand = weight frags loaded direct from global (L2, prefetched).
// B-operand = x k-slices staged in LDS (double-buffered, 1 barrier/slice).
// acc[et][ot2]: lane(m_,q) holds edge et*16+m_, outcols w*32+ot2*16+q*4+{0..3}.
__global__ __launch_bounds__(256, 2)
void edge_kernel(const __bf16* __restrict__ xb,
                 const float4* __restrict__ e_geo,
                 const int2* __restrict__ e_nodes,
                 const float2* __restrict__ e_gate,
                 const __bf16* __restrict__ We1T,
                 const float* __restrict__ We1,   // f32, rows 256/257 (r2, edge_attr)
                 const float* __restrict__ be1,
                 const __bf16* __restrict__ We2T,
                 const float* __restrict__ be2,
                 const float* __restrict__ Wc,
                 const float* __restrict__ bc,
                 float* __restrict__ msum,
                 float* __restrict__ coordsum) {
    // union region: [Xs dbuf 2x8192 | A2 at +16384, 128x136 bf16 = 34816] = 51200 B
    //               reduce phase reuses [0, 33792) as Mf (64 rows x 132 f32)
    __shared__ __align__(16) char smU[51200];
    __shared__ float s_r2[128], s_ea[128], s_sg[128], s_g[128];
    __shared__ float s_diff[384];
    __shared__ int s_dst[128], s_src[128];
    __shared__ float s_gp[512];            // [wave][edge]
    __shared__ int s_gstart[130];
    __shared__ int s_gdst[128];
    __shared__ unsigned long long s_mask[2];

    __bf16* A2 = (__bf16*)(smU + 16384);
    float* Mf = (float*)smU;

    const int t = threadIdx.x;
    const int e0 = blockIdx.x * 128;
    const int w = t >> 6;
    const int lane = t & 63;
    const int m_ = lane & 15;
    const int q = lane >> 4;

    // per-edge scalars (sorted order, precomputed records)
    if (t < 128) {
        float4 g = e_geo[e0 + t];
        int2 nd = e_nodes[e0 + t];
        float2 gt = e_gate[e0 + t];
        s_diff[t * 3 + 0] = g.x; s_diff[t * 3 + 1] = g.y; s_diff[t * 3 + 2] = g.z;
        s_r2[t] = g.w;
        s_ea[t] = gt.x;
        s_sg[t] = gt.y;
        s_src[t] = nd.x;
        s_dst[t] = nd.y;
    }
    __syncthreads();

    // group boundary flags -> per-wave ballot masks (waves 0,1 cover edges 0..127)
    {
        bool flag = false;
        if (t < 128) flag = (t == 0) || (s_dst[t] != s_dst[t - 1]);
        unsigned long long mk = __ballot(flag);
        if (t == 0) s_mask[0] = mk;
        if (t == 64) s_mask[1] = mk;
    }
    __syncthreads();

    // compact group list
    if (t < 128) {
        int wv = t >> 6;
        int ln = t & 63;
        unsigned long long mw = s_mask[wv];
        if ((mw >> ln) & 1ull) {
            int base = (wv == 1) ? __popcll(s_mask[0]) : 0;
            int gi = base + __popcll(mw & ((1ull << ln) - 1ull));
            s_gstart[gi] = t;
            s_gdst[gi] = s_dst[t];
        }
    }
    const int G = __popcll(s_mask[0]) + __popcll(s_mask[1]);
    if (t == 0) s_gstart[G] = 128;
    // (visible after the first K-loop barrier)

    // staging assignment: thread t stages chunks for edges elA and elB=elA+64
    const int elA = t >> 2;
    const int chA = (t & 3) * 8;
    const int dA = s_dst[elA], sA = s_src[elA];
    const int dB = s_dst[elA + 64], sB = s_src[elA + 64];
    const __bf16* pAd = xb + (long)dA * 128 + chA;
    const __bf16* pAs = xb + (long)sA * 128 + chA;
    const __bf16* pBd = xb + (long)dB * 128 + chA;
    const __bf16* pBs = xb + (long)sB * 128 + chA;

    // weight fragment base pointers (wave-owned outcols)
    const __bf16* w1p0 = We1T + (long)(w * 32 + m_) * 256 + q * 8;
    const __bf16* w1p1 = We1T + (long)(w * 32 + 16 + m_) * 256 + q * 8;

    f32x4_t acc[8][2];
#pragma unroll
    for (int et = 0; et < 8; ++et) {
        acc[et][0] = (f32x4_t){0.f, 0.f, 0.f, 0.f};
        acc[et][1] = (f32x4_t){0.f, 0.f, 0.f, 0.f};
    }

    // prologue: x slice 0 + weight frags slice 0
    uint4 xrA = *(const uint4*)(pAd);
    uint4 xrB = *(const uint4*)(pBd);
    bf16x8_t wf0 = *(const bf16x8_t*)(w1p0);
    bf16x8_t wf1 = *(const bf16x8_t*)(w1p1);

    // ---- layer 1: K = 256 (k 0..127 = x[dst], 128..255 = x[src]) ----
#pragma unroll
    for (int ks = 0; ks < 8; ++ks) {
        __bf16* Xs = (__bf16*)(smU + (ks & 1) * 8192);
        *(uint4*)(Xs + elA * 32 + chA) = xrA;
        *(uint4*)(Xs + (elA + 64) * 32 + chA) = xrB;
        bf16x8_t nwf0, nwf1;
        if (ks < 7) {
            int off = ((ks + 1) & 3) * 32;
            xrA = *(const uint4*)(((ks + 1) < 4 ? pAd : pAs) + off);
            xrB = *(const uint4*)(((ks + 1) < 4 ? pBd : pBs) + off);
            nwf0 = *(const bf16x8_t*)(w1p0 + (ks + 1) * 32);
            nwf1 = *(const bf16x8_t*)(w1p1 + (ks + 1) * 32);
        }
        __syncthreads();
#pragma unroll
        for (int et = 0; et < 8; ++et) {
            bf16x8_t xf = *(const bf16x8_t*)(Xs + (et * 16 + m_) * 32 + q * 8);
            acc[et][0] = __builtin_amdgcn_mfma_f32_16x16x32_bf16(wf0, xf, acc[et][0], 0, 0, 0);
            acc[et][1] = __builtin_amdgcn_mfma_f32_16x16x32_bf16(wf1, xf, acc[et][1], 0, 0, 0);
        }
        if (ks < 7) { wf0 = nwf0; wf1 = nwf1; }
    }

    // epilogue 1: + b + r2*W[256] + ea*W[257], SiLU -> A2 (bf16)
    {
        const int oc0 = w * 32 + q * 4;
        const int oc1 = oc0 + 16;
        float4 b1a = *(const float4*)(be1 + oc0);
        float4 b1b = *(const float4*)(be1 + oc1);
        float4 w6a = *(const float4*)(We1 + 256 * 128 + oc0);
        float4 w6b = *(const float4*)(We1 + 256 * 128 + oc1);
        float4 w7a = *(const float4*)(We1 + 257 * 128 + oc0);
        float4 w7b = *(const float4*)(We1 + 257 * 128 + oc1);
#pragma unroll
        for (int et = 0; et < 8; ++et) {
            int e = et * 16 + m_;
            float r2 = s_r2[e], ea = s_ea[e];
            union { __bf16 h[4]; uint2 u2; } pk;
            pk.h[0] = (__bf16)silu_f(acc[et][0][0] + b1a.x + r2 * w6a.x + ea * w7a.x);
            pk.h[1] = (__bf16)silu_f(acc[et][0][1] + b1a.y + r2 * w6a.y + ea * w7a.y);
            pk.h[2] = (__bf16)silu_f(acc[et][0][2] + b1a.z + r2 * w6a.z + ea * w7a.z);
            pk.h[3] = (__bf16)silu_f(acc[et][0][3] + b1a.w + r2 * w6a.w + ea * w7a.w);
            *(uint2*)(A2 + e * 136 + oc0) = pk.u2;
            pk.h[0] = (__bf16)silu_f(acc[et][1][0] + b1b.x + r2 * w6b.x + ea * w7b.x);
            pk.h[1] = (__bf16)silu_f(acc[et][1][1] + b1b.y + r2 * w6b.y + ea * w7b.y);
            pk.h[2] = (__bf16)silu_f(acc[et][1][2] + b1b.z + r2 * w6b.z + ea * w7b.z);
            pk.h[3] = (__bf16)silu_f(acc[et][1][3] + b1b.w + r2 * w6b.w + ea * w7b.w);
            *(uint2*)(A2 + e * 136 + oc1) = pk.u2;
        }
    }

#pragma unroll
    for (int et = 0; et < 8; ++et) {
        acc[et][0] = (f32x4_t){0.f, 0.f, 0.f, 0.f};
        acc[et][1] = (f32x4_t){0.f, 0.f, 0.f, 0.f};
    }
    __syncthreads();   // A2 complete before cross-wave reads

    // ---- layer 2: K = 128, B-operand = A2 rows; no in-loop barriers ----
    {
        const __bf16* w2p0 = We2T + (long)(w * 32 + m_) * 128 + q * 8;
        const __bf16* w2p1 = We2T + (long)(w * 32 + 16 + m_) * 128 + q * 8;
        bf16x8_t f0 = *(const bf16x8_t*)(w2p0);
        bf16x8_t f1 = *(const bf16x8_t*)(w2p1);
#pragma unroll
        for (int ks = 0; ks < 4; ++ks) {
            bf16x8_t n0, n1;
            if (ks < 3) {
                n0 = *(const bf16x8_t*)(w2p0 + (ks + 1) * 32);
                n1 = *(const bf16x8_t*)(w2p1 + (ks + 1) * 32);
            }
#pragma unroll
            for (int et = 0; et < 8; ++et) {
                bf16x8_t af = *(const bf16x8_t*)(A2 + (et * 16 + m_) * 136 + ks * 32 + q * 8);
                acc[et][0] = __builtin_amdgcn_mfma_f32_16x16x32_bf16(f0, af, acc[et][0], 0, 0, 0);
                acc[et][1] = __builtin_amdgcn_mfma_f32_16x16x32_bf16(f1, af, acc[et][1], 0, 0, 0);
            }
            if (ks < 3) { f0 = n0; f1 = n1; }
        }
    }

    // epilogue 2: + b, SiLU, * s[src]; gamma partials (per-wave 32-col dot)
    {
        const int oc0 = w * 32 + q * 4;
        const int oc1 = oc0 + 16;
        float4 b2a = *(const float4*)(be2 + oc0);
        float4 b2b = *(const float4*)(be2 + oc1);
        float4 wca = *(const float4*)(Wc + oc0);
        float4 wcb = *(const float4*)(Wc + oc1);
#pragma unroll
        for (int et = 0; et < 8; ++et) {
            int e = et * 16 + m_;
            float sg = s_sg[e];
            f32x4_t v0 = acc[et][0], v1 = acc[et][1];
            v0[0] = silu_f(v0[0] + b2a.x) * sg; v0[1] = silu_f(v0[1] + b2a.y) * sg;
            v0[2] = silu_f(v0[2] + b2a.z) * sg; v0[3] = silu_f(v0[3] + b2a.w) * sg;
            v1[0] = silu_f(v1[0] + b2b.x) * sg; v1[1] = silu_f(v1[1] + b2b.y) * sg;
            v1[2] = silu_f(v1[2] + b2b.z) * sg; v1[3] = silu_f(v1[3] + b2b.w) * sg;
            acc[et][0] = v0; acc[et][1] = v1;
            float gp = v0[0] * wca.x + v0[1] * wca.y + v0[2] * wca.z + v0[3] * wca.w
                     + v1[0] * wcb.x + v1[1] * wcb.y + v1[2] * wcb.z + v1[3] * wcb.w;
            gp += __shfl_xor(gp, 16);
            gp += __shfl_xor(gp, 32);
            if (q == 0) s_gp[w * 128 + e] = gp;
        }
    }
    __syncthreads();   // B1: all A2 reads + s_gp writes done (Mf may clobber A2)

    // Mf phase 0: edges 0..63 (et 0..3)
    {
        const int oc0 = w * 32 + q * 4;
        const int oc1 = oc0 + 16;
#pragma unroll
        for (int et = 0; et < 4; ++et) {
            int e = et * 16 + m_;
            *(f32x4_t*)(Mf + e * 132 + oc0) = acc[et][0];
            *(f32x4_t*)(Mf + e * 132 + oc1) = acc[et][1];
        }
    }
    __syncthreads();   // B2: Mf ph0 ready

    if (t < 128)
        s_g[t] = bc[0] + s_gp[t] + s_gp[128 + t] + s_gp[256 + t] + s_gp[384 + t];

    // msum tasks, phase 0 (rows 0..63)
    const int T0 = G * 128;
    for (int task = t; task < T0; task += 256) {
        int g = task >> 7, c = task & 127;
        int lo = s_gstart[g], hi = s_gstart[g + 1];
        if (lo < 64) {
            int h = hi < 64 ? hi : 64;
            float sum = 0.f;
            for (int r = lo; r < h; ++r) sum += Mf[r * 132 + c];
            atomicAdd(&msum[(long)s_gdst[g] * 128 + c], sum);
        }
    }
    __syncthreads();   // B4: ph0 reads done

    // Mf phase 1: edges 64..127 (et 4..7)
    {
        const int oc0 = w * 32 + q * 4;
        const int oc1 = oc0 + 16;
#pragma unroll
        for (int et = 4; et < 8; ++et) {
            int e = et * 16 + m_ - 64;
            *(f32x4_t*)(Mf + e * 132 + oc0) = acc[et][0];
            *(f32x4_t*)(Mf + e * 132 + oc1) = acc[et][1];
        }
    }
    __syncthreads();   // B5: Mf ph1 + s_g ready

    // msum tasks phase 1 (rows 64..127) + coord tasks (full 128 rows)
    for (int task = t; task < G * 131; task += 256) {
        if (task < T0) {
            int g = task >> 7, c = task & 127;
            int lo = s_gstart[g], hi = s_gstart[g + 1];
            if (hi > 64) {
                int l = lo > 64 ? lo : 64;
                float sum = 0.f;
                for (int r = l; r < hi; ++r) sum += Mf[(r - 64) * 132 + c];
                atomicAdd(&msum[(long)s_gdst[g] * 128 + c], sum);
            }
        } else {
            int idx = task - T0;
            int g = idx / 3, ax = idx % 3;
            int lo = s_gstart[g], hi = s_gstart[g + 1];
            float sum = 0.f;
            for (int r = lo; r < hi; ++r) sum += s_g[r] * s_diff[r * 3 + ax];
            atomicAdd(&coordsum[s_gdst[g] * 3 + ax], sum);
        }
    }
}

// ---------------- node kernel: normalize agg + 2-layer node MLP + pos update ----------------
__global__ __launch_bounds__(256, 2)
void node_kernel(const __bf16* __restrict__ xb,
                 const float* __restrict__ msum,
                 const int* __restrict__ off,
                 const __bf16* __restrict__ Wn1T,
                 const float* __restrict__ bn1,
                 const __bf16* __restrict__ Wn2T,
                 const float* __restrict__ bn2,
                 const float* __restrict__ pos,
                 const float* __restrict__ csum,
                 float* __restrict__ xout,
                 float* __restrict__ pout) {
    __shared__ __align__(16) __bf16 Abf[64 * 264];
    __shared__ __align__(16) __bf16 Wt[128 * 56];
    __shared__ __align__(16) __bf16 A2[64 * 136];

    const int t = threadIdx.x;
    const int r0 = blockIdx.x * 64;
    const int w = t >> 6;
    const int lane = t & 63;
    const int m_ = lane & 15;
    const int q = lane >> 4;

    if (t < 192) {
        int node = r0 + t / 3;
        if (node < NN) {
            int dg = off[node + 1] - off[node];
            float inv = 1.f / (float)(dg < 1 ? 1 : dg);
            int fl = node * 3 + t % 3;
            pout[fl] = pos[fl] + csum[fl] * inv;
        }
    }

    for (int i = 0; i < 8; ++i) {
        int id = t + 256 * i;
        int rl = id >> 5, ch = id & 31;
        int row = r0 + rl;
        int c8 = (ch & 15) * 8;
        union { __bf16 h[8]; uint4 u; } pk;
        if (row < NN) {
            if (ch < 16) {
                pk.u = *(const uint4*)(xb + (long)row * 128 + c8);
            } else {
                const float* mp = msum + (long)row * 128 + c8;
                int dg = off[row + 1] - off[row];
                float inv = 1.f / (float)(dg < 1 ? 1 : dg);
#pragma unroll
                for (int j = 0; j < 8; ++j) pk.h[j] = (__bf16)(mp[j] * inv);
            }
        } else {
            pk.u = make_uint4(0, 0, 0, 0);
        }
        *(uint4*)(Abf + rl * 264 + ((ch < 16) ? 0 : 128) + c8) = pk.u;
    }
    __syncthreads();

    f32x4_t acc[8];
#pragma unroll
    for (int ct = 0; ct < 8; ++ct) acc[ct] = (f32x4_t){0.f, 0.f, 0.f, 0.f};

    for (int ks = 0; ks < 8; ++ks) {
#pragma unroll
        for (int i = 0; i < 2; ++i) {
            int c = t + 256 * i;
            int n = c >> 2, ko = (c & 3) * 8;
            uint4 v = *(const uint4*)(Wn1T + n * 256 + ks * 32 + ko);
            *(uint4*)(Wt + n * 56 + ko) = v;
        }
        __syncthreads();
        bf16x8_t a = *(const bf16x8_t*)(Abf + (w * 16 + m_) * 264 + ks * 32 + q * 8);
#pragma unroll
        for (int ct = 0; ct < 8; ++ct) {
            bf16x8_t b = *(const bf16x8_t*)(Wt + (ct * 16 + m_) * 56 + q * 8);
            acc[ct] = __builtin_amdgcn_mfma_f32_16x16x32_bf16(a, b, acc[ct], 0, 0, 0);
        }
        __syncthreads();
    }
#pragma unroll
    for (int ct = 0; ct < 8; ++ct) {
        int c = ct * 16 + m_;
        float b1 = bn1[c];
#pragma unroll
        for (int r = 0; r < 4; ++r) {
            int el = w * 16 + q * 4 + r;
            float v = acc[ct][r] + b1;
            A2[el * 136 + c] = (__bf16)silu_f(v);
        }
    }
    __syncthreads();

#pragma unroll
    for (int ct = 0; ct < 8; ++ct) acc[ct] = (f32x4_t){0.f, 0.f, 0.f, 0.f};

    for (int ks = 0; ks < 4; ++ks) {
#pragma unroll
        for (int i = 0; i < 2; ++i) {
            int c = t + 256 * i;
            int n = c >> 2, ko = (c & 3) * 8;
            uint4 v = *(const uint4*)(Wn2T + n * 128 + ks * 32 + ko);
            *(uint4*)(Wt + n * 56 + ko) = v;
        }
        __syncthreads();
        bf16x8_t a = *(const bf16x8_t*)(A2 + (w * 16 + m_) * 136 + ks * 32 + q * 8);
#pragma unroll
        for (int ct = 0; ct < 8; ++ct) {
            bf16x8_t b = *(const bf16x8_t*)(Wt + (ct * 16 + m_) * 56 + q * 8);
            acc[ct] = __builtin_amdgcn_mfma_f32_16x16x32_bf16(a, b, acc[ct], 0, 0, 0);
        }
        __syncthreads();
    }
#pragma unroll
    for (int ct = 0; ct < 8; ++ct) {
        int c = ct * 16 + m_;
        float b2 = bn2[c];
#pragma unroll
        for (int r = 0; r < 4; ++r) {
            int el = w * 16 + q * 4 + r;
            int row = r0 + el;
            if (row < NN) xout[(long)row * 128 + c] = acc[ct][r] + b2;
        }
    }
}

extern "C" void kernel_launch(void* const* d_in, const int* in_sizes, int n_in,
                              void* d_out, int out_size, void* d_ws, size_t ws_size,
                              hipStream_t stream) {
    const float* x     = (const float*)d_in[0];
    const float* pos   = (const float*)d_in[1];
    const int*   eidx  = (const int*)d_in[2];
    const float* eattr = (const float*)d_in[3];
    const float* s     = (const float*)d_in[4];
    const float* We1   = (const float*)d_in[5];
    const float* be1   = (const float*)d_in[6];
    const float* We2   = (const float*)d_in[7];
    const float* be2   = (const float*)d_in[8];
    const float* Wn1   = (const float*)d_in[9];
    const float* bn1   = (const float*)d_in[10];
    const float* Wn2   = (const float*)d_in[11];
    const float* bn2   = (const float*)d_in[12];
    const float* Wc    = (const float*)d_in[13];
    const float* bc    = (const float*)d_in[14];

    char* ws = (char*)d_ws;
    __bf16* xb     = (__bf16*)(ws);                 // 12,800,000
    __bf16* We1T   = (__bf16*)(ws + 12800000);      //     65,536
    __bf16* We2T   = (__bf16*)(ws + 12865536);      //     32,768
    __bf16* Wn1T   = (__bf16*)(ws + 12898304);      //     65,536
    __bf16* Wn2T   = (__bf16*)(ws + 12963840);      //     32,768
    float*  msum   = (float*)(ws + 12996608);       // 25,600,000
    float*  csum   = (float*)(ws + 38596608);       //    600,000
    int*    hist   = (int*)(ws + 39196608);         //    200,000
    int*    off    = (int*)(ws + 39396608);         //    200,064
    int*    cursor = (int*)(ws + 39596672);         //    200,064
    float4* e_geo  = (float4*)(ws + 39796736);      // 12,800,000 (16B aligned)
    int2*   e_nodes= (int2*)(ws + 52596736);        //  6,400,000
    float2* e_gate = (float2*)(ws + 58996736);      //  6,400,000
    int*    bsum   = (int*)(ws + 65396736);         //      1,024 (end 65,397,760)

    float* xout = (float*)d_out;
    float* pout = xout + (size_t)NN * 128;

    // zero msum + csum + hist (contiguous, 26.4 MB)
    hipMemsetAsync(ws + 12996608, 0, 26400000, stream);
    prep_kernel<<<1024, 256, 0, stream>>>(x, We1, We2, Wn1, Wn2, eidx,
                                          xb, We1T, We2T, Wn1T, Wn2T, hist);
    scan_a<<<SCAN_BLOCKS, 256, 0, stream>>>(hist, bsum);
    scan_b<<<1, 256, 0, stream>>>(bsum);
    scan_c<<<SCAN_BLOCKS, 256, 0, stream>>>(hist, bsum, off, cursor);
    scatter_kernel<<<(EE + 255) / 256, 256, 0, stream>>>(eidx, pos, eattr, s, cursor,
                                                         e_geo, e_nodes, e_gate);
    edge_kernel<<<EE / 128, 256, 0, stream>>>(xb, e_geo, e_nodes, e_gate,
                                              We1T, We1, be1, We2T, be2, Wc, bc,
                                              msum, csum);
    node_kernel<<<(NN + 63) / 64, 256, 0, stream>>>(xb, msum, off, Wn1T, bn1, Wn2T, bn2,
                                                    pos, csum, xout, pout);
}